// Round 10
// baseline (534.443 us; speedup 1.0000x reference)
//
#include <hip/hip_runtime.h>

#define NN 100000
#define NE 1600000
#define DD 64
#define BSH 9
#define BSZ 512                          // nodes per bucket
#define NBKT 196                         // ceil(NN/512)
#define CHUNK 8192                       // edges per scatter block
#define NCH ((NE + CHUNK - 1) / CHUNK)   // 196
#define CSR2_CAP (NE + 16 * NN + 1024)   // sum of pad16(deg+1)

// ---------------- zero init ----------------

__global__ void k_zero(int* __restrict__ bcnt,
                       float* __restrict__ h2sA, float* __restrict__ h2sB) {
    int t = threadIdx.x;
    if (t < NBKT) bcnt[t] = 0;
    if (t < DD) h2sA[(size_t)NN * DD + t] = 0.f;                 // dummy row A
    if (t >= 64 && t < 128) h2sB[(size_t)NN * DD + (t - 64)] = 0.f;  // dummy row B
}

// ---------------- P1: coarse bucket histogram ----------------

__global__ __launch_bounds__(256) void k_bcount(const int* __restrict__ ei,
                                                int* __restrict__ bcnt) {
    __shared__ int h[NBKT];
    int t = threadIdx.x;
    for (int i = t; i < NBKT; i += 256) h[i] = 0;
    __syncthreads();
    int base = blockIdx.x * CHUNK;
    for (int i = t; i < CHUNK; i += 256) {
        int e = base + i;
        if (e < NE) atomicAdd(&h[ei[NE + e] >> BSH], 1);
    }
    __syncthreads();
    for (int i = t; i < NBKT; i += 256)
        if (h[i]) atomicAdd(&bcnt[i], h[i]);
}

// ---------------- P1s: parallel scan of bucket counts ----------------

__global__ __launch_bounds__(256) void k_bscan(const int* __restrict__ bcnt,
                                               int* __restrict__ bbase,
                                               int* __restrict__ bcur) {
    __shared__ int s[256];
    int t = threadIdx.x;
    int v = (t < NBKT) ? bcnt[t] : 0;
    s[t] = v;
    __syncthreads();
    for (int o = 1; o < 256; o <<= 1) {
        int x = (t >= o) ? s[t - o] : 0;
        __syncthreads();
        s[t] += x;
        __syncthreads();
    }
    int ex = s[t] - v;
    if (t < NBKT) { bbase[t] = ex; bcur[t] = ex; }
    if (t == NBKT) bbase[NBKT] = ex;
}

// ---------------- P2: scatter edges into bucket-grouped packed lists ----------------
// packed = s | (dlocal << 17);  s < 2^17, dlocal < 512.

__global__ __launch_bounds__(256) void k_bscat(const int* __restrict__ ei,
                                               int* __restrict__ bcur,
                                               int* __restrict__ bkt) {
    __shared__ int h[NBKT], rbase[NBKT], rcur[NBKT];
    int t = threadIdx.x;
    for (int i = t; i < NBKT; i += 256) h[i] = 0;
    __syncthreads();
    int cb = blockIdx.x * CHUNK;
    int s[32], d[32];
#pragma unroll
    for (int i = 0; i < 32; ++i) {
        int e = cb + t + 256 * i;
        if (e < NE) {
            s[i] = ei[e];
            d[i] = ei[NE + e];
            atomicAdd(&h[d[i] >> BSH], 1);
        } else {
            d[i] = -1;
        }
    }
    __syncthreads();
    for (int i = t; i < NBKT; i += 256) {
        int c = h[i];
        rbase[i] = c ? atomicAdd(&bcur[i], c) : 0;
        rcur[i] = 0;
    }
    __syncthreads();
#pragma unroll
    for (int i = 0; i < 32; ++i) {
        if (d[i] >= 0) {
            int b = d[i] >> BSH;
            int pos = rbase[b] + atomicAdd(&rcur[b], 1);
            bkt[pos] = s[i] | ((d[i] & (BSZ - 1)) << 17);
        }
    }
}

// ---------------- P3a: per-bucket node counts (LDS), dis, padded totals ----------------
// padded row = ceil((deg+1)/16)*16

__global__ __launch_bounds__(256) void k_ncnt(const int* __restrict__ bbase,
                                              const int* __restrict__ bkt,
                                              int* __restrict__ ncnt,
                                              int* __restrict__ bptot,
                                              double* __restrict__ dis) {
    __shared__ int cnt[BSZ];
    __shared__ int red[256];
    int b = blockIdx.x, t = threadIdx.x;
    cnt[t] = 0; cnt[t + 256] = 0;
    __syncthreads();
    int beg = bbase[b], end = bbase[b + 1];
    for (int j = beg + t; j < end; j += 256)
        atomicAdd(&cnt[bkt[j] >> 17], 1);
    __syncthreads();
    int nb = b * BSZ;
    int n0 = nb + t, n1 = nb + t + 256;
    int c0 = cnt[t], c1 = cnt[t + 256];
    int p0 = (n0 < NN) ? ((c0 + 16) & ~15) : 0;
    int p1 = (n1 < NN) ? ((c1 + 16) & ~15) : 0;
    if (n0 < NN) { ncnt[n0] = c0; dis[n0] = 1.0 / sqrt((double)(c0 + 1)); }
    if (n1 < NN) { ncnt[n1] = c1; dis[n1] = 1.0 / sqrt((double)(c1 + 1)); }
    red[t] = p0 + p1;
    __syncthreads();
    for (int o = 128; o > 0; o >>= 1) {
        if (t < o) red[t] += red[t + o];
        __syncthreads();
    }
    if (t == 0) bptot[b] = red[0];
}

// ---------------- P3b: parallel scan of padded bucket totals ----------------

__global__ __launch_bounds__(256) void k_pscan(const int* __restrict__ bptot,
                                               int* __restrict__ pbase,
                                               int* __restrict__ rp2) {
    __shared__ int s[256];
    int t = threadIdx.x;
    int v = (t < NBKT) ? bptot[t] : 0;
    s[t] = v;
    __syncthreads();
    for (int o = 1; o < 256; o <<= 1) {
        int x = (t >= o) ? s[t - o] : 0;
        __syncthreads();
        s[t] += x;
        __syncthreads();
    }
    int ex = s[t] - v;
    if (t < NBKT) pbase[t] = ex;
    if (t == NBKT) rp2[NN] = ex;
}

// ---------------- P3c: per-bucket rp2 + csr2 fill (LDS scan + LDS cursors) ----------------

__global__ __launch_bounds__(256) void k_bfill(const int* __restrict__ bbase,
                                               const int* __restrict__ bkt,
                                               const int* __restrict__ ncnt,
                                               const int* __restrict__ pbase,
                                               int* __restrict__ rp2,
                                               int* __restrict__ csr2) {
    __shared__ int cur[BSZ];
    __shared__ int s2[256];
    int b = blockIdx.x, t = threadIdx.x;
    int nb = b * BSZ;
    int gbase = pbase[b];
    int n0 = nb + 2 * t, n1 = nb + 2 * t + 1;
    int c0 = (n0 < NN) ? ncnt[n0] : -1;
    int c1 = (n1 < NN) ? ncnt[n1] : -1;
    int q0 = (c0 >= 0) ? ((c0 + 16) & ~15) : 0;
    int q1 = (c1 >= 0) ? ((c1 + 16) & ~15) : 0;
    s2[t] = q0 + q1;
    __syncthreads();
    for (int o = 1; o < 256; o <<= 1) {              // Hillis-Steele inclusive scan
        int v = (t >= o) ? s2[t - o] : 0;
        __syncthreads();
        s2[t] += v;
        __syncthreads();
    }
    int ex = s2[t] - (q0 + q1);                      // exclusive offset of node n0
    if (c0 >= 0) { int g = gbase + ex;      rp2[n0] = g; csr2[g] = n0; cur[2 * t]     = ex + 1; }
    if (c1 >= 0) { int g = gbase + ex + q0; rp2[n1] = g; csr2[g] = n1; cur[2 * t + 1] = ex + q0 + 1; }
    __syncthreads();
    int beg = bbase[b], end = bbase[b + 1];
    for (int j = beg + t; j < end; j += 256) {
        int pk = bkt[j];
        int pos = gbase + atomicAdd(&cur[pk >> 17], 1);
        csr2[pos] = pk & 0x1FFFF;
    }
    __syncthreads();
    if (c0 >= 0) { int e0 = ex + q0;      for (int j = cur[2 * t];     j < e0; ++j) csr2[gbase + j] = NN; }
    if (c1 >= 0) { int e1 = ex + q0 + q1; for (int j = cur[2 * t + 1]; j < e1; ++j) csr2[gbase + j] = NN; }
}

// ---------------- GEMM compute macro body (shared by k_gemm / k_fused) ----------------
// reads sIn[128*65], sW[64*64]; thread t: rows (t>>3)*4..+3, cols (t&7)*8..+7

__device__ __forceinline__ void gemm_phase(const float* sW, const float* sIn,
                                           const double* dis, float* h2s, int brow, int t) {
    int cg = t & 7;
    int rg = t >> 3;
    const float* sInB = &sIn[rg * 4 * 65];

    float aE[4][8], aO[4][8];
#pragma unroll
    for (int i = 0; i < 4; ++i)
#pragma unroll
        for (int j = 0; j < 8; ++j) { aE[i][j] = 0.f; aO[i][j] = 0.f; }

#pragma unroll 4
    for (int k = 0; k < DD; k += 2) {
        float4 w0 = *(const float4*)&sW[k * DD + cg * 8];
        float4 w1 = *(const float4*)&sW[k * DD + cg * 8 + 4];
        float4 w2 = *(const float4*)&sW[(k + 1) * DD + cg * 8];
        float4 w3 = *(const float4*)&sW[(k + 1) * DD + cg * 8 + 4];
        float wv0[8] = {w0.x, w0.y, w0.z, w0.w, w1.x, w1.y, w1.z, w1.w};
        float wv1[8] = {w2.x, w2.y, w2.z, w2.w, w3.x, w3.y, w3.z, w3.w};
#pragma unroll
        for (int i = 0; i < 4; ++i) {
            float a0 = sInB[i * 65 + k];
            float a1 = sInB[i * 65 + k + 1];
#pragma unroll
            for (int j = 0; j < 8; ++j) {
                aE[i][j] = fmaf(a0, wv0[j], aE[i][j]);
                aO[i][j] = fmaf(a1, wv1[j], aO[i][j]);
            }
        }
    }

#pragma unroll
    for (int i = 0; i < 4; ++i) {
        int row = brow + rg * 4 + i;
        if (row < NN) {
            double dr = dis[row];
            float o[8];
#pragma unroll
            for (int j = 0; j < 8; ++j)
                o[j] = (float)((double)(aE[i][j] + aO[i][j]) * dr);
            *(float4*)&h2s[(size_t)row * DD + cg * 8]     = make_float4(o[0], o[1], o[2], o[3]);
            *(float4*)&h2s[(size_t)row * DD + cg * 8 + 4] = make_float4(o[4], o[5], o[6], o[7]);
        }
    }
}

// ---------------- layer-1 GEMM: h2s = (x @ W) * dis[row] ----------------

__global__ __launch_bounds__(256) void k_gemm(const float* __restrict__ in,
                                              const float* __restrict__ W,
                                              const double* __restrict__ dis,
                                              float* __restrict__ h2s) {
    __shared__ float sW[DD * DD];
    __shared__ float sIn[128 * 65];
    int t = threadIdx.x;
    int brow = blockIdx.x * 128;
#pragma unroll
    for (int i = 0; i < 16; ++i) sW[t + 256 * i] = W[t + 256 * i];
#pragma unroll
    for (int i = 0; i < 32; ++i) {
        int idx = t + 256 * i;
        int rr = idx >> 6, kk = idx & 63;
        int gr = brow + rr; if (gr >= NN) gr = NN - 1;
        sIn[rr * 65 + kk] = in[(size_t)gr * DD + kk];
    }
    __syncthreads();
    gemm_phase(sW, sIn, dis, h2s, brow, t);
}

// ---------------- fused: aggr(layer l) -> LDS -> gemm(layer l+1) ----------------
// wave w aggregates rows brow+w*32..+31 (lane = feature) with bias+ELU into sIn,
// then the block runs the gemm phase into h2s_new. ELU always applied (layers 1-3).

__global__ __launch_bounds__(256) void k_fused(const int* __restrict__ rp2,
                                               const int* __restrict__ csr2,
                                               const float* __restrict__ h2s_old,
                                               const double* __restrict__ dis,
                                               const float* __restrict__ bias,
                                               const float* __restrict__ W,
                                               float* __restrict__ h2s_new) {
    __shared__ float sW[DD * DD];
    __shared__ float sIn[128 * 65];
    int t = threadIdx.x;
    int brow = blockIdx.x * 128;
#pragma unroll
    for (int i = 0; i < 16; ++i) sW[t + 256 * i] = W[t + 256 * i];

    int lane = t & 63;
    int w = t >> 6;
    float bv = bias[lane];
    for (int rr = w * 32; rr < w * 32 + 32; ++rr) {
        int r = brow + rr;
        if (r >= NN) { sIn[rr * 65 + lane] = 0.f; continue; }   // last block only
        int beg = __builtin_amdgcn_readfirstlane(rp2[r]);
        int end = __builtin_amdgcn_readfirstlane(rp2[r + 1]);
        double a0 = 0.0, a1 = 0.0, a2 = 0.0, a3 = 0.0;
        for (int j = beg; j < end; j += 16) {
            int4 i0 = *(const int4*)&csr2[j];
            int4 i1 = *(const int4*)&csr2[j + 4];
            int4 i2 = *(const int4*)&csr2[j + 8];
            int4 i3 = *(const int4*)&csr2[j + 12];
            float v0  = h2s_old[(size_t)(unsigned)i0.x * DD + lane];
            float v1  = h2s_old[(size_t)(unsigned)i0.y * DD + lane];
            float v2  = h2s_old[(size_t)(unsigned)i0.z * DD + lane];
            float v3  = h2s_old[(size_t)(unsigned)i0.w * DD + lane];
            float v4  = h2s_old[(size_t)(unsigned)i1.x * DD + lane];
            float v5  = h2s_old[(size_t)(unsigned)i1.y * DD + lane];
            float v6  = h2s_old[(size_t)(unsigned)i1.z * DD + lane];
            float v7  = h2s_old[(size_t)(unsigned)i1.w * DD + lane];
            float v8  = h2s_old[(size_t)(unsigned)i2.x * DD + lane];
            float v9  = h2s_old[(size_t)(unsigned)i2.y * DD + lane];
            float v10 = h2s_old[(size_t)(unsigned)i2.z * DD + lane];
            float v11 = h2s_old[(size_t)(unsigned)i2.w * DD + lane];
            float v12 = h2s_old[(size_t)(unsigned)i3.x * DD + lane];
            float v13 = h2s_old[(size_t)(unsigned)i3.y * DD + lane];
            float v14 = h2s_old[(size_t)(unsigned)i3.z * DD + lane];
            float v15 = h2s_old[(size_t)(unsigned)i3.w * DD + lane];
            a0 += (double)v0;  a1 += (double)v1;  a2 += (double)v2;  a3 += (double)v3;
            a0 += (double)v4;  a1 += (double)v5;  a2 += (double)v6;  a3 += (double)v7;
            a0 += (double)v8;  a1 += (double)v9;  a2 += (double)v10; a3 += (double)v11;
            a0 += (double)v12; a1 += (double)v13; a2 += (double)v14; a3 += (double)v15;
        }
        float vf = (float)(dis[r] * ((a0 + a1) + (a2 + a3)) + (double)bv);
        if (vf <= 0.f) vf = expm1f(vf);          // ELU
        sIn[rr * 65 + lane] = vf;
    }
    __syncthreads();
    gemm_phase(sW, sIn, dis, h2s_new, brow, t);
}

// ---------------- final aggregate: lane = feature, writes d_out (no ELU) ----------------

__global__ __launch_bounds__(256) void k_aggr(const int* __restrict__ rp2,
                                              const int* __restrict__ csr2,
                                              const float* __restrict__ h2s,
                                              const double* __restrict__ dis,
                                              const float* __restrict__ b,
                                              float* __restrict__ out) {
    int gid = blockIdx.x * 256 + threadIdx.x;
    int node = gid >> 6;
    int lane = gid & 63;
    int beg = __builtin_amdgcn_readfirstlane(rp2[node]);
    int end = __builtin_amdgcn_readfirstlane(rp2[node + 1]);
    double a0 = 0.0, a1 = 0.0, a2 = 0.0, a3 = 0.0;
    for (int j = beg; j < end; j += 16) {
        int4 i0 = *(const int4*)&csr2[j];
        int4 i1 = *(const int4*)&csr2[j + 4];
        int4 i2 = *(const int4*)&csr2[j + 8];
        int4 i3 = *(const int4*)&csr2[j + 12];
        float v0  = h2s[(size_t)(unsigned)i0.x * DD + lane];
        float v1  = h2s[(size_t)(unsigned)i0.y * DD + lane];
        float v2  = h2s[(size_t)(unsigned)i0.z * DD + lane];
        float v3  = h2s[(size_t)(unsigned)i0.w * DD + lane];
        float v4  = h2s[(size_t)(unsigned)i1.x * DD + lane];
        float v5  = h2s[(size_t)(unsigned)i1.y * DD + lane];
        float v6  = h2s[(size_t)(unsigned)i1.z * DD + lane];
        float v7  = h2s[(size_t)(unsigned)i1.w * DD + lane];
        float v8  = h2s[(size_t)(unsigned)i2.x * DD + lane];
        float v9  = h2s[(size_t)(unsigned)i2.y * DD + lane];
        float v10 = h2s[(size_t)(unsigned)i2.z * DD + lane];
        float v11 = h2s[(size_t)(unsigned)i2.w * DD + lane];
        float v12 = h2s[(size_t)(unsigned)i3.x * DD + lane];
        float v13 = h2s[(size_t)(unsigned)i3.y * DD + lane];
        float v14 = h2s[(size_t)(unsigned)i3.z * DD + lane];
        float v15 = h2s[(size_t)(unsigned)i3.w * DD + lane];
        a0 += (double)v0;  a1 += (double)v1;  a2 += (double)v2;  a3 += (double)v3;
        a0 += (double)v4;  a1 += (double)v5;  a2 += (double)v6;  a3 += (double)v7;
        a0 += (double)v8;  a1 += (double)v9;  a2 += (double)v10; a3 += (double)v11;
        a0 += (double)v12; a1 += (double)v13; a2 += (double)v14; a3 += (double)v15;
    }
    double sum = (a0 + a1) + (a2 + a3);
    out[gid] = (float)(dis[node] * sum + (double)b[lane]);
}

// ---------------- launch ----------------

static inline size_t align256(size_t x) { return (x + 255) & ~(size_t)255; }

extern "C" void kernel_launch(void* const* d_in, const int* in_sizes, int n_in,
                              void* d_out, int out_size, void* d_ws, size_t ws_size,
                              hipStream_t stream) {
    const float* x  = (const float*)d_in[0];
    const int*   ei = (const int*)d_in[1];
    const float* W1 = (const float*)d_in[3];
    const float* b1 = (const float*)d_in[4];
    const float* W2 = (const float*)d_in[5];
    const float* b2 = (const float*)d_in[6];
    const float* W3 = (const float*)d_in[7];
    const float* b3 = (const float*)d_in[8];
    const float* W4 = (const float*)d_in[9];
    const float* b4 = (const float*)d_in[10];
    float* out = (float*)d_out;

    char* ws = (char*)d_ws;
    size_t off = 0;
    float*  h2sA  = (float*) (ws + off); off = align256(off + (size_t)(NN + 1) * DD * sizeof(float));
    float*  h2sB  = (float*) (ws + off); off = align256(off + (size_t)(NN + 1) * DD * sizeof(float));
    double* dis   = (double*)(ws + off); off = align256(off + (size_t)NN * sizeof(double));
    int*    ncnt  = (int*)   (ws + off); off = align256(off + (size_t)NN * sizeof(int));
    int*    rp2   = (int*)   (ws + off); off = align256(off + (size_t)(NN + 1) * sizeof(int));
    int*    bcnt  = (int*)   (ws + off); off = align256(off + (size_t)(NBKT + 1) * sizeof(int));
    int*    bbase = (int*)   (ws + off); off = align256(off + (size_t)(NBKT + 1) * sizeof(int));
    int*    bcur  = (int*)   (ws + off); off = align256(off + (size_t)(NBKT + 1) * sizeof(int));
    int*    bptot = (int*)   (ws + off); off = align256(off + (size_t)(NBKT + 1) * sizeof(int));
    int*    pbase = (int*)   (ws + off); off = align256(off + (size_t)(NBKT + 1) * sizeof(int));
    int*    bkt   = (int*)   (ws + off); off = align256(off + (size_t)NE * sizeof(int));
    int*    csr2  = (int*)   (ws + off); off = align256(off + (size_t)CSR2_CAP * sizeof(int));

    k_zero<<<1, 256, 0, stream>>>(bcnt, h2sA, h2sB);
    k_bcount<<<NCH, 256, 0, stream>>>(ei, bcnt);
    k_bscan<<<1, 256, 0, stream>>>(bcnt, bbase, bcur);
    k_bscat<<<NCH, 256, 0, stream>>>(ei, bcur, bkt);
    k_ncnt<<<NBKT, 256, 0, stream>>>(bbase, bkt, ncnt, bptot, dis);
    k_pscan<<<1, 256, 0, stream>>>(bptot, pbase, rp2);
    k_bfill<<<NBKT, 256, 0, stream>>>(bbase, bkt, ncnt, pbase, rp2, csr2);

    const int NGB = (NN + 127) / 128;   // 782
    k_gemm <<<NGB, 256, 0, stream>>>(x, W1, dis, h2sA);
    k_fused<<<NGB, 256, 0, stream>>>(rp2, csr2, h2sA, dis, b1, W2, h2sB);
    k_fused<<<NGB, 256, 0, stream>>>(rp2, csr2, h2sB, dis, b2, W3, h2sA);
    k_fused<<<NGB, 256, 0, stream>>>(rp2, csr2, h2sA, dis, b3, W4, h2sB);
    k_aggr <<<NN / 4, 256, 0, stream>>>(rp2, csr2, h2sB, dis, b4, out);
}

// Round 11
// 378.231 us; speedup vs baseline: 1.4130x; 1.4130x over previous
//
#include <hip/hip_runtime.h>

#define NN 100000
#define NE 1600000
#define DD 64
#define BSH 9
#define BSZ 512                          // nodes per bucket
#define NBKT 196                         // ceil(NN/512)
#define BCAP 16384                       // bkt row capacity (mean 8192, sigma~90)
#define CHUNK 8192                       // edges per scatter block
#define NCH ((NE + CHUNK - 1) / CHUNK)   // 196
#define CSR2_CAP (NE + 16 * NN + 1024)   // sum of pad16(deg+1)

// ---------------- zero init ----------------

__global__ void k_zero(int* __restrict__ bcur, int* __restrict__ gcur,
                       float* __restrict__ h2sA, float* __restrict__ h2sB) {
    int t = threadIdx.x;
    if (t < NBKT) bcur[t] = 0;
    if (t == 255) *gcur = 0;
    if (t < DD) h2sA[(size_t)NN * DD + t] = 0.f;                 // dummy row A
    if (t >= 64 && t < 128) h2sB[(size_t)NN * DD + (t - 64)] = 0.f;  // dummy row B
}

// ---------------- P1: scatter edges into fixed-cap bucket rows ----------------
// packed = s | (dlocal << 17);  s < 2^17, dlocal < 512. bcur[b] ends as count.

__global__ __launch_bounds__(256) void k_bscat(const int* __restrict__ ei,
                                               int* __restrict__ bcur,
                                               int* __restrict__ bkt) {
    __shared__ int h[NBKT], rbase[NBKT], rcur[NBKT];
    int t = threadIdx.x;
    for (int i = t; i < NBKT; i += 256) h[i] = 0;
    __syncthreads();
    int cb = blockIdx.x * CHUNK;
    int s[32], d[32];
#pragma unroll
    for (int i = 0; i < 32; ++i) {
        int e = cb + t + 256 * i;
        if (e < NE) {
            s[i] = ei[e];
            d[i] = ei[NE + e];
            atomicAdd(&h[d[i] >> BSH], 1);
        } else {
            d[i] = -1;
        }
    }
    __syncthreads();
    for (int i = t; i < NBKT; i += 256) {
        int c = h[i];
        rbase[i] = c ? atomicAdd(&bcur[i], c) : 0;
        rcur[i] = 0;
    }
    __syncthreads();
#pragma unroll
    for (int i = 0; i < 32; ++i) {
        if (d[i] >= 0) {
            int b = d[i] >> BSH;
            int pos = rbase[b] + atomicAdd(&rcur[b], 1);
            bkt[(size_t)b * BCAP + pos] = s[i] | ((d[i] & (BSZ - 1)) << 17);
        }
    }
}

// ---------------- P2: per-bucket count + scan + atomic space reservation + csr2 fill ----
// One block per bucket. csr2 space reserved with one atomicAdd(gcur) per bucket;
// per-node rbeg/rlen recorded (bucket order in csr2 is irrelevant to aggr).

__global__ __launch_bounds__(256) void k_merge(const int* __restrict__ bcur,
                                               const int* __restrict__ bkt,
                                               int* __restrict__ gcur,
                                               int* __restrict__ rbeg,
                                               int* __restrict__ rlen,
                                               double* __restrict__ dis,
                                               int* __restrict__ csr2) {
    __shared__ int cnt[BSZ];
    __shared__ int cur[BSZ];
    __shared__ int s2[256];
    __shared__ int sbase;
    int b = blockIdx.x, t = threadIdx.x;
    cnt[t] = 0; cnt[t + 256] = 0;
    __syncthreads();
    int ec = bcur[b];
    const int* row = bkt + (size_t)b * BCAP;
    for (int j = t; j < ec; j += 256)
        atomicAdd(&cnt[row[j] >> 17], 1);
    __syncthreads();
    int nb = b * BSZ;
    int n0 = nb + 2 * t, n1 = nb + 2 * t + 1;
    int c0 = (n0 < NN) ? cnt[2 * t] : -1;
    int c1 = (n1 < NN) ? cnt[2 * t + 1] : -1;
    int q0 = (c0 >= 0) ? ((c0 + 16) & ~15) : 0;      // pad16(deg+1)
    int q1 = (c1 >= 0) ? ((c1 + 16) & ~15) : 0;
    s2[t] = q0 + q1;
    __syncthreads();
    for (int o = 1; o < 256; o <<= 1) {              // Hillis-Steele inclusive scan
        int v = (t >= o) ? s2[t - o] : 0;
        __syncthreads();
        s2[t] += v;
        __syncthreads();
    }
    if (t == 255) sbase = atomicAdd(gcur, s2[255]);  // reserve csr2 space
    __syncthreads();
    int base = sbase;
    int ex = s2[t] - (q0 + q1);                      // exclusive offset of node n0
    if (c0 >= 0) {
        rbeg[n0] = base + ex; rlen[n0] = q0;
        dis[n0] = 1.0 / sqrt((double)(c0 + 1));
        csr2[base + ex] = n0;                        // self entry
        cur[2 * t] = ex + 1;
    }
    if (c1 >= 0) {
        rbeg[n1] = base + ex + q0; rlen[n1] = q1;
        dis[n1] = 1.0 / sqrt((double)(c1 + 1));
        csr2[base + ex + q0] = n1;
        cur[2 * t + 1] = ex + q0 + 1;
    }
    __syncthreads();
    for (int j = t; j < ec; j += 256) {
        int pk = row[j];
        int pos = base + atomicAdd(&cur[pk >> 17], 1);
        csr2[pos] = pk & 0x1FFFF;
    }
    __syncthreads();
    if (c0 >= 0) { int e0 = ex + q0;      for (int j = cur[2 * t];     j < e0; ++j) csr2[base + j] = NN; }
    if (c1 >= 0) { int e1 = ex + q0 + q1; for (int j = cur[2 * t + 1]; j < e1; ++j) csr2[base + j] = NN; }
}

// ---------------- layer-1 GEMM: h2s = (x @ W) * dis[row] ----------------

__global__ __launch_bounds__(256) void k_gemm(const float* __restrict__ in,
                                              const float* __restrict__ W,
                                              const double* __restrict__ dis,
                                              float* __restrict__ h2s) {
    __shared__ float sW[DD * DD];
    __shared__ float sIn[128 * 65];
    int t = threadIdx.x;
    int brow = blockIdx.x * 128;
#pragma unroll
    for (int i = 0; i < 16; ++i) sW[t + 256 * i] = W[t + 256 * i];
#pragma unroll
    for (int i = 0; i < 32; ++i) {
        int idx = t + 256 * i;
        int rr = idx >> 6, kk = idx & 63;
        int gr = brow + rr; if (gr >= NN) gr = NN - 1;
        sIn[rr * 65 + kk] = in[(size_t)gr * DD + kk];
    }
    __syncthreads();
    int cg = t & 7;
    int rg = t >> 3;
    const float* sInB = &sIn[rg * 4 * 65];

    float aE[4][8], aO[4][8];
#pragma unroll
    for (int i = 0; i < 4; ++i)
#pragma unroll
        for (int j = 0; j < 8; ++j) { aE[i][j] = 0.f; aO[i][j] = 0.f; }

#pragma unroll 4
    for (int k = 0; k < DD; k += 2) {
        float4 w0 = *(const float4*)&sW[k * DD + cg * 8];
        float4 w1 = *(const float4*)&sW[k * DD + cg * 8 + 4];
        float4 w2 = *(const float4*)&sW[(k + 1) * DD + cg * 8];
        float4 w3 = *(const float4*)&sW[(k + 1) * DD + cg * 8 + 4];
        float wv0[8] = {w0.x, w0.y, w0.z, w0.w, w1.x, w1.y, w1.z, w1.w};
        float wv1[8] = {w2.x, w2.y, w2.z, w2.w, w3.x, w3.y, w3.z, w3.w};
#pragma unroll
        for (int i = 0; i < 4; ++i) {
            float a0 = sInB[i * 65 + k];
            float a1 = sInB[i * 65 + k + 1];
#pragma unroll
            for (int j = 0; j < 8; ++j) {
                aE[i][j] = fmaf(a0, wv0[j], aE[i][j]);
                aO[i][j] = fmaf(a1, wv1[j], aO[i][j]);
            }
        }
    }

#pragma unroll
    for (int i = 0; i < 4; ++i) {
        int row = brow + rg * 4 + i;
        if (row < NN) {
            double dr = dis[row];
            float o[8];
#pragma unroll
            for (int j = 0; j < 8; ++j)
                o[j] = (float)((double)(aE[i][j] + aO[i][j]) * dr);
            *(float4*)&h2s[(size_t)row * DD + cg * 8]     = make_float4(o[0], o[1], o[2], o[3]);
            *(float4*)&h2s[(size_t)row * DD + cg * 8 + 4] = make_float4(o[4], o[5], o[6], o[7]);
        }
    }
}

// ---------------- fused aggr + bias/ELU + readlane-GEMM + dis  ----------------
// Wave = one node; lane = feature. After aggregation, vf = A[node][lane];
// next-layer GEMM by broadcasting A[node][k] via v_readlane against W column
// 'lane' held in 64 VGPRs. No LDS -> occupancy limited only by VGPRs.

__global__ __launch_bounds__(256) void k_fag(const int* __restrict__ rbeg,
                                             const int* __restrict__ rlen,
                                             const int* __restrict__ csr2,
                                             const float* __restrict__ h2s_old,
                                             const double* __restrict__ dis,
                                             const float* __restrict__ bias,
                                             const float* __restrict__ W,
                                             float* __restrict__ h2s_new) {
    int t = threadIdx.x;
    int lane = t & 63;
    float wk[64];
#pragma unroll
    for (int k = 0; k < 64; ++k) wk[k] = W[k * DD + lane];   // W column 'lane'
    float bv = bias[lane];
    int wglob = blockIdx.x * 4 + (t >> 6);
    int nwaves = gridDim.x * 4;
    for (int node = wglob; node < NN; node += nwaves) {
        int beg = __builtin_amdgcn_readfirstlane(rbeg[node]);
        int end = beg + __builtin_amdgcn_readfirstlane(rlen[node]);
        double a0 = 0.0, a1 = 0.0, a2 = 0.0, a3 = 0.0;
        for (int j = beg; j < end; j += 8) {
            int4 i0 = *(const int4*)&csr2[j];
            int4 i1 = *(const int4*)&csr2[j + 4];
            float v0 = h2s_old[(size_t)(unsigned)i0.x * DD + lane];
            float v1 = h2s_old[(size_t)(unsigned)i0.y * DD + lane];
            float v2 = h2s_old[(size_t)(unsigned)i0.z * DD + lane];
            float v3 = h2s_old[(size_t)(unsigned)i0.w * DD + lane];
            float v4 = h2s_old[(size_t)(unsigned)i1.x * DD + lane];
            float v5 = h2s_old[(size_t)(unsigned)i1.y * DD + lane];
            float v6 = h2s_old[(size_t)(unsigned)i1.z * DD + lane];
            float v7 = h2s_old[(size_t)(unsigned)i1.w * DD + lane];
            a0 += (double)v0; a1 += (double)v1;
            a2 += (double)v2; a3 += (double)v3;
            a0 += (double)v4; a1 += (double)v5;
            a2 += (double)v6; a3 += (double)v7;
        }
        double dn = dis[node];
        float vf = (float)(dn * ((a0 + a1) + (a2 + a3)) + (double)bv);
        if (vf <= 0.f) vf = expm1f(vf);          // ELU (layers 1..3 only)
        // GEMM row: h2s_new[node][lane] = (sum_k A[node][k] * W[k][lane]) * dis[node]
        int vb = __float_as_int(vf);
        float accE = 0.f, accO = 0.f;
#pragma unroll
        for (int k = 0; k < 64; k += 2) {
            float h0 = __int_as_float(__builtin_amdgcn_readlane(vb, k));
            float h1 = __int_as_float(__builtin_amdgcn_readlane(vb, k + 1));
            accE = fmaf(h0, wk[k], accE);
            accO = fmaf(h1, wk[k + 1], accO);
        }
        h2s_new[(size_t)node * DD + lane] = (float)((double)(accE + accO) * dn);
    }
}

// ---------------- final aggregate: writes d_out (bias, no ELU) ----------------

__global__ __launch_bounds__(256) void k_aggr(const int* __restrict__ rbeg,
                                              const int* __restrict__ rlen,
                                              const int* __restrict__ csr2,
                                              const float* __restrict__ h2s,
                                              const double* __restrict__ dis,
                                              const float* __restrict__ b,
                                              float* __restrict__ out) {
    int gid = blockIdx.x * 256 + threadIdx.x;
    int node = gid >> 6;
    int lane = gid & 63;
    int beg = __builtin_amdgcn_readfirstlane(rbeg[node]);
    int end = beg + __builtin_amdgcn_readfirstlane(rlen[node]);
    double a0 = 0.0, a1 = 0.0, a2 = 0.0, a3 = 0.0;
    for (int j = beg; j < end; j += 16) {
        int4 i0 = *(const int4*)&csr2[j];
        int4 i1 = *(const int4*)&csr2[j + 4];
        int4 i2 = *(const int4*)&csr2[j + 8];
        int4 i3 = *(const int4*)&csr2[j + 12];
        float v0  = h2s[(size_t)(unsigned)i0.x * DD + lane];
        float v1  = h2s[(size_t)(unsigned)i0.y * DD + lane];
        float v2  = h2s[(size_t)(unsigned)i0.z * DD + lane];
        float v3  = h2s[(size_t)(unsigned)i0.w * DD + lane];
        float v4  = h2s[(size_t)(unsigned)i1.x * DD + lane];
        float v5  = h2s[(size_t)(unsigned)i1.y * DD + lane];
        float v6  = h2s[(size_t)(unsigned)i1.z * DD + lane];
        float v7  = h2s[(size_t)(unsigned)i1.w * DD + lane];
        float v8  = h2s[(size_t)(unsigned)i2.x * DD + lane];
        float v9  = h2s[(size_t)(unsigned)i2.y * DD + lane];
        float v10 = h2s[(size_t)(unsigned)i2.z * DD + lane];
        float v11 = h2s[(size_t)(unsigned)i2.w * DD + lane];
        float v12 = h2s[(size_t)(unsigned)i3.x * DD + lane];
        float v13 = h2s[(size_t)(unsigned)i3.y * DD + lane];
        float v14 = h2s[(size_t)(unsigned)i3.z * DD + lane];
        float v15 = h2s[(size_t)(unsigned)i3.w * DD + lane];
        a0 += (double)v0;  a1 += (double)v1;  a2 += (double)v2;  a3 += (double)v3;
        a0 += (double)v4;  a1 += (double)v5;  a2 += (double)v6;  a3 += (double)v7;
        a0 += (double)v8;  a1 += (double)v9;  a2 += (double)v10; a3 += (double)v11;
        a0 += (double)v12; a1 += (double)v13; a2 += (double)v14; a3 += (double)v15;
    }
    double sum = (a0 + a1) + (a2 + a3);
    out[gid] = (float)(dis[node] * sum + (double)b[lane]);
}

// ---------------- launch ----------------

static inline size_t align256(size_t x) { return (x + 255) & ~(size_t)255; }

extern "C" void kernel_launch(void* const* d_in, const int* in_sizes, int n_in,
                              void* d_out, int out_size, void* d_ws, size_t ws_size,
                              hipStream_t stream) {
    const float* x  = (const float*)d_in[0];
    const int*   ei = (const int*)d_in[1];
    const float* W1 = (const float*)d_in[3];
    const float* b1 = (const float*)d_in[4];
    const float* W2 = (const float*)d_in[5];
    const float* b2 = (const float*)d_in[6];
    const float* W3 = (const float*)d_in[7];
    const float* b3 = (const float*)d_in[8];
    const float* W4 = (const float*)d_in[9];
    const float* b4 = (const float*)d_in[10];
    float* out = (float*)d_out;

    char* ws = (char*)d_ws;
    size_t off = 0;
    float*  h2sA = (float*) (ws + off); off = align256(off + (size_t)(NN + 1) * DD * sizeof(float));
    float*  h2sB = (float*) (ws + off); off = align256(off + (size_t)(NN + 1) * DD * sizeof(float));
    double* dis  = (double*)(ws + off); off = align256(off + (size_t)NN * sizeof(double));
    int*    rbeg = (int*)   (ws + off); off = align256(off + (size_t)NN * sizeof(int));
    int*    rlen = (int*)   (ws + off); off = align256(off + (size_t)NN * sizeof(int));
    int*    bcur = (int*)   (ws + off); off = align256(off + (size_t)(NBKT + 1) * sizeof(int));
    int*    gcur = (int*)   (ws + off); off = align256(off + 256 * sizeof(int));
    int*    bkt  = (int*)   (ws + off); off = align256(off + (size_t)NBKT * BCAP * sizeof(int));
    int*    csr2 = (int*)   (ws + off); off = align256(off + (size_t)CSR2_CAP * sizeof(int));

    k_zero <<<1, 256, 0, stream>>>(bcur, gcur, h2sA, h2sB);
    k_bscat<<<NCH, 256, 0, stream>>>(ei, bcur, bkt);
    k_merge<<<NBKT, 256, 0, stream>>>(bcur, bkt, gcur, rbeg, rlen, dis, csr2);

    const int NGB = (NN + 127) / 128;   // 782
    k_gemm<<<NGB, 256, 0, stream>>>(x, W1, dis, h2sA);
    k_fag <<<2048, 256, 0, stream>>>(rbeg, rlen, csr2, h2sA, dis, b1, W2, h2sB);
    k_fag <<<2048, 256, 0, stream>>>(rbeg, rlen, csr2, h2sB, dis, b2, W3, h2sA);
    k_fag <<<2048, 256, 0, stream>>>(rbeg, rlen, csr2, h2sA, dis, b3, W4, h2sB);
    k_aggr<<<NN / 4, 256, 0, stream>>>(rbeg, rlen, csr2, h2sB, dis, b4, out);
}

// Round 12
// 370.932 us; speedup vs baseline: 1.4408x; 1.0197x over previous
//
#include <hip/hip_runtime.h>

#define NN 100000
#define NE 1600000
#define DD 64
#define BSH 9
#define BSZ 512                          // nodes per bucket
#define NBKT 196                         // ceil(NN/512)
#define BCAP 16384                       // bkt row capacity (mean 8163, ~91 sigma margin)
#define CHUNK 8192                       // edges per scatter block
#define NCH ((NE + CHUNK - 1) / CHUNK)   // 196
#define CSR2_CAP (NE + 16 * NN + 1024)   // sum of pad16(deg+1)

// ---------------- zero init ----------------

__global__ void k_zero(int* __restrict__ bcur, int* __restrict__ gcur,
                       float* __restrict__ h2s) {
    int t = threadIdx.x;
    if (t < NBKT) bcur[t] = 0;
    if (t == 255) *gcur = 0;
    if (t < DD) h2s[(size_t)NN * DD + t] = 0.f;   // dummy row = 0
}

// ---------------- P1: scatter edges into fixed-cap bucket rows ----------------
// packed = s | (dlocal << 17);  s < 2^17, dlocal < 512. bcur[b] ends as count.

__global__ __launch_bounds__(256) void k_bscat(const int* __restrict__ ei,
                                               int* __restrict__ bcur,
                                               int* __restrict__ bkt) {
    __shared__ int h[NBKT], rbase[NBKT], rcur[NBKT];
    int t = threadIdx.x;
    for (int i = t; i < NBKT; i += 256) h[i] = 0;
    __syncthreads();
    int cb = blockIdx.x * CHUNK;
    int s[32], d[32];
#pragma unroll
    for (int i = 0; i < 32; ++i) {
        int e = cb + t + 256 * i;
        if (e < NE) {
            s[i] = ei[e];
            d[i] = ei[NE + e];
            atomicAdd(&h[d[i] >> BSH], 1);
        } else {
            d[i] = -1;
        }
    }
    __syncthreads();
    for (int i = t; i < NBKT; i += 256) {
        int c = h[i];
        rbase[i] = c ? atomicAdd(&bcur[i], c) : 0;
        rcur[i] = 0;
    }
    __syncthreads();
#pragma unroll
    for (int i = 0; i < 32; ++i) {
        if (d[i] >= 0) {
            int b = d[i] >> BSH;
            int pos = rbase[b] + atomicAdd(&rcur[b], 1);
            bkt[(size_t)b * BCAP + pos] = s[i] | ((d[i] & (BSZ - 1)) << 17);
        }
    }
}

// ---------------- P2: per-bucket count + scan + atomic space reservation + csr2 fill ----
// One block per bucket. csr2 space reserved with one atomicAdd(gcur) per bucket;
// per-node rbeg/rlen recorded (bucket order in csr2 is irrelevant to aggr).

__global__ __launch_bounds__(256) void k_merge(const int* __restrict__ bcur,
                                               const int* __restrict__ bkt,
                                               int* __restrict__ gcur,
                                               int* __restrict__ rbeg,
                                               int* __restrict__ rlen,
                                               double* __restrict__ dis,
                                               int* __restrict__ csr2) {
    __shared__ int cnt[BSZ];
    __shared__ int cur[BSZ];
    __shared__ int s2[256];
    __shared__ int sbase;
    int b = blockIdx.x, t = threadIdx.x;
    cnt[t] = 0; cnt[t + 256] = 0;
    __syncthreads();
    int ec = bcur[b];
    const int* row = bkt + (size_t)b * BCAP;
    for (int j = t; j < ec; j += 256)
        atomicAdd(&cnt[row[j] >> 17], 1);
    __syncthreads();
    int nb = b * BSZ;
    int n0 = nb + 2 * t, n1 = nb + 2 * t + 1;
    int c0 = (n0 < NN) ? cnt[2 * t] : -1;
    int c1 = (n1 < NN) ? cnt[2 * t + 1] : -1;
    int q0 = (c0 >= 0) ? ((c0 + 16) & ~15) : 0;      // pad16(deg+1)
    int q1 = (c1 >= 0) ? ((c1 + 16) & ~15) : 0;
    s2[t] = q0 + q1;
    __syncthreads();
    for (int o = 1; o < 256; o <<= 1) {              // Hillis-Steele inclusive scan
        int v = (t >= o) ? s2[t - o] : 0;
        __syncthreads();
        s2[t] += v;
        __syncthreads();
    }
    if (t == 255) sbase = atomicAdd(gcur, s2[255]);  // reserve csr2 space
    __syncthreads();
    int base = sbase;
    int ex = s2[t] - (q0 + q1);                      // exclusive offset of node n0
    if (c0 >= 0) {
        rbeg[n0] = base + ex; rlen[n0] = q0;
        dis[n0] = 1.0 / sqrt((double)(c0 + 1));
        csr2[base + ex] = n0;                        // self entry
        cur[2 * t] = ex + 1;
    }
    if (c1 >= 0) {
        rbeg[n1] = base + ex + q0; rlen[n1] = q1;
        dis[n1] = 1.0 / sqrt((double)(c1 + 1));
        csr2[base + ex + q0] = n1;
        cur[2 * t + 1] = ex + q0 + 1;
    }
    __syncthreads();
    for (int j = t; j < ec; j += 256) {
        int pk = row[j];
        int pos = base + atomicAdd(&cur[pk >> 17], 1);
        csr2[pos] = pk & 0x1FFFF;
    }
    __syncthreads();
    if (c0 >= 0) { int e0 = ex + q0;      for (int j = cur[2 * t];     j < e0; ++j) csr2[base + j] = NN; }
    if (c1 >= 0) { int e1 = ex + q0 + q1; for (int j = cur[2 * t + 1]; j < e1; ++j) csr2[base + j] = NN; }
}

// ---------------- GEMM: h2s = (in @ W) * dis[row] ----------------
// 128 rows/block; thread t: rows (t>>3)*4..+3, cols (t&7)*8..+7. sIn padded to 65.

__global__ __launch_bounds__(256) void k_gemm(const float* __restrict__ in,
                                              const float* __restrict__ W,
                                              const double* __restrict__ dis,
                                              float* __restrict__ h2s) {
    __shared__ float sW[DD * DD];
    __shared__ float sIn[128 * 65];
    int t = threadIdx.x;
    int brow = blockIdx.x * 128;
#pragma unroll
    for (int i = 0; i < 16; ++i) sW[t + 256 * i] = W[t + 256 * i];
#pragma unroll
    for (int i = 0; i < 32; ++i) {
        int idx = t + 256 * i;
        int rr = idx >> 6, kk = idx & 63;
        int gr = brow + rr; if (gr >= NN) gr = NN - 1;
        sIn[rr * 65 + kk] = in[(size_t)gr * DD + kk];
    }
    __syncthreads();
    int cg = t & 7;
    int rg = t >> 3;
    const float* sInB = &sIn[rg * 4 * 65];

    float aE[4][8], aO[4][8];
#pragma unroll
    for (int i = 0; i < 4; ++i)
#pragma unroll
        for (int j = 0; j < 8; ++j) { aE[i][j] = 0.f; aO[i][j] = 0.f; }

#pragma unroll 4
    for (int k = 0; k < DD; k += 2) {
        float4 w0 = *(const float4*)&sW[k * DD + cg * 8];
        float4 w1 = *(const float4*)&sW[k * DD + cg * 8 + 4];
        float4 w2 = *(const float4*)&sW[(k + 1) * DD + cg * 8];
        float4 w3 = *(const float4*)&sW[(k + 1) * DD + cg * 8 + 4];
        float wv0[8] = {w0.x, w0.y, w0.z, w0.w, w1.x, w1.y, w1.z, w1.w};
        float wv1[8] = {w2.x, w2.y, w2.z, w2.w, w3.x, w3.y, w3.z, w3.w};
#pragma unroll
        for (int i = 0; i < 4; ++i) {
            float a0 = sInB[i * 65 + k];
            float a1 = sInB[i * 65 + k + 1];
#pragma unroll
            for (int j = 0; j < 8; ++j) {
                aE[i][j] = fmaf(a0, wv0[j], aE[i][j]);
                aO[i][j] = fmaf(a1, wv1[j], aO[i][j]);
            }
        }
    }

#pragma unroll
    for (int i = 0; i < 4; ++i) {
        int row = brow + rg * 4 + i;
        if (row < NN) {
            double dr = dis[row];
            float o[8];
#pragma unroll
            for (int j = 0; j < 8; ++j)
                o[j] = (float)((double)(aE[i][j] + aO[i][j]) * dr);
            *(float4*)&h2s[(size_t)row * DD + cg * 8]     = make_float4(o[0], o[1], o[2], o[3]);
            *(float4*)&h2s[(size_t)row * DD + cg * 8 + 4] = make_float4(o[4], o[5], o[6], o[7]);
        }
    }
}

// ---------------- gather-aggregate: lane = feature, 16 gathers in flight ----------------

__global__ __launch_bounds__(256) void k_aggr(const int* __restrict__ rbeg,
                                              const int* __restrict__ rlen,
                                              const int* __restrict__ csr2,
                                              const float* __restrict__ h2s,
                                              const double* __restrict__ dis,
                                              const float* __restrict__ b,
                                              float* __restrict__ out,
                                              int apply_elu) {
    int gid = blockIdx.x * 256 + threadIdx.x;
    int node = gid >> 6;
    int lane = gid & 63;
    int beg = __builtin_amdgcn_readfirstlane(rbeg[node]);
    int end = beg + __builtin_amdgcn_readfirstlane(rlen[node]);
    double a0 = 0.0, a1 = 0.0, a2 = 0.0, a3 = 0.0;
    for (int j = beg; j < end; j += 16) {
        int4 i0 = *(const int4*)&csr2[j];
        int4 i1 = *(const int4*)&csr2[j + 4];
        int4 i2 = *(const int4*)&csr2[j + 8];
        int4 i3 = *(const int4*)&csr2[j + 12];
        float v0  = h2s[(size_t)(unsigned)i0.x * DD + lane];
        float v1  = h2s[(size_t)(unsigned)i0.y * DD + lane];
        float v2  = h2s[(size_t)(unsigned)i0.z * DD + lane];
        float v3  = h2s[(size_t)(unsigned)i0.w * DD + lane];
        float v4  = h2s[(size_t)(unsigned)i1.x * DD + lane];
        float v5  = h2s[(size_t)(unsigned)i1.y * DD + lane];
        float v6  = h2s[(size_t)(unsigned)i1.z * DD + lane];
        float v7  = h2s[(size_t)(unsigned)i1.w * DD + lane];
        float v8  = h2s[(size_t)(unsigned)i2.x * DD + lane];
        float v9  = h2s[(size_t)(unsigned)i2.y * DD + lane];
        float v10 = h2s[(size_t)(unsigned)i2.z * DD + lane];
        float v11 = h2s[(size_t)(unsigned)i2.w * DD + lane];
        float v12 = h2s[(size_t)(unsigned)i3.x * DD + lane];
        float v13 = h2s[(size_t)(unsigned)i3.y * DD + lane];
        float v14 = h2s[(size_t)(unsigned)i3.z * DD + lane];
        float v15 = h2s[(size_t)(unsigned)i3.w * DD + lane];
        a0 += (double)v0;  a1 += (double)v1;  a2 += (double)v2;  a3 += (double)v3;
        a0 += (double)v4;  a1 += (double)v5;  a2 += (double)v6;  a3 += (double)v7;
        a0 += (double)v8;  a1 += (double)v9;  a2 += (double)v10; a3 += (double)v11;
        a0 += (double)v12; a1 += (double)v13; a2 += (double)v14; a3 += (double)v15;
    }
    double sum = (a0 + a1) + (a2 + a3);
    float vf = (float)(dis[node] * sum + (double)b[lane]);
    if (apply_elu && vf <= 0.f) vf = expm1f(vf);
    out[gid] = vf;
}

// ---------------- launch ----------------

static inline size_t align256(size_t x) { return (x + 255) & ~(size_t)255; }

extern "C" void kernel_launch(void* const* d_in, const int* in_sizes, int n_in,
                              void* d_out, int out_size, void* d_ws, size_t ws_size,
                              hipStream_t stream) {
    const float* x  = (const float*)d_in[0];
    const int*   ei = (const int*)d_in[1];
    const float* W1 = (const float*)d_in[3];
    const float* b1 = (const float*)d_in[4];
    const float* W2 = (const float*)d_in[5];
    const float* b2 = (const float*)d_in[6];
    const float* W3 = (const float*)d_in[7];
    const float* b3 = (const float*)d_in[8];
    const float* W4 = (const float*)d_in[9];
    const float* b4 = (const float*)d_in[10];
    float* out = (float*)d_out;

    char* ws = (char*)d_ws;
    size_t off = 0;
    float*  h2s  = (float*) (ws + off); off = align256(off + (size_t)(NN + 1) * DD * sizeof(float));
    float*  A    = (float*) (ws + off); off = align256(off + (size_t)NN * DD * sizeof(float));
    double* dis  = (double*)(ws + off); off = align256(off + (size_t)NN * sizeof(double));
    int*    rbeg = (int*)   (ws + off); off = align256(off + (size_t)NN * sizeof(int));
    int*    rlen = (int*)   (ws + off); off = align256(off + (size_t)NN * sizeof(int));
    int*    bcur = (int*)   (ws + off); off = align256(off + (size_t)(NBKT + 1) * sizeof(int));
    int*    gcur = (int*)   (ws + off); off = align256(off + 256 * sizeof(int));
    int*    bkt  = (int*)   (ws + off); off = align256(off + (size_t)NBKT * BCAP * sizeof(int));
    int*    csr2 = (int*)   (ws + off); off = align256(off + (size_t)CSR2_CAP * sizeof(int));

    k_zero <<<1, 256, 0, stream>>>(bcur, gcur, h2s);
    k_bscat<<<NCH, 256, 0, stream>>>(ei, bcur, bkt);
    k_merge<<<NBKT, 256, 0, stream>>>(bcur, bkt, gcur, rbeg, rlen, dis, csr2);

    struct Layer { const float* in; const float* W; const float* b; float* o; int elu; };
    Layer L[4] = {
        { x,   W1, b1, A,   1 },
        { A,   W2, b2, out, 1 },
        { out, W3, b3, A,   1 },
        { A,   W4, b4, out, 0 },
    };

    const int NGB = (NN + 127) / 128;   // 782
    for (int l = 0; l < 4; ++l) {
        k_gemm<<<NGB, 256, 0, stream>>>(L[l].in, L[l].W, dis, h2s);
        k_aggr<<<NN / 4, 256, 0, stream>>>(rbeg, rlen, csr2, h2s, dis,
                                           L[l].b, L[l].o, L[l].elu);
    }
}